// Round 10
// baseline (627.242 us; speedup 1.0000x reference)
//
#include <hip/hip_runtime.h>
#include <hip/hip_bf16.h>

// Problem constants
#define B_ 4
#define S1_ 64
#define S2_ 256
#define D_ 256
#define H_ 8
#define HD_ 32
#define F_ 1024
#define EPS_ 1e-5f
#define NEG_ 0.01f

typedef __attribute__((ext_vector_type(8))) short bfrag;   // 8 x bf16 (4 VGPRs)
typedef __attribute__((ext_vector_type(4))) float f32x4;   // MFMA C/D
typedef __attribute__((ext_vector_type(8))) unsigned short us8;
typedef __attribute__((ext_vector_type(4))) unsigned short us4;

__device__ __forceinline__ unsigned short bf16rn(float f) {
    union { float f; unsigned int u; } c; c.f = f;
    unsigned int u = c.u;
    u = (u + 0x7FFFu + ((u >> 16) & 1u)) >> 16;   // round-to-nearest-even
    return (unsigned short)u;
}
__device__ __forceinline__ float bf2f(unsigned short s) {
    union { unsigned int u; float f; } c; c.u = ((unsigned int)s) << 16;
    return c.f;
}

// async global->LDS, 16B per lane. lds base must be wave-uniform; HW adds lane*16.
__device__ __forceinline__ void gload_lds16(const void* g, void* l) {
    __builtin_amdgcn_global_load_lds(
        (const __attribute__((address_space(1))) void*)g,
        (__attribute__((address_space(3))) void*)l,
        16, 0, 0);
}

// ---------------------------------------------------------------------------
// x (fp32) -> xb16 (bf16), flat cast. 8 elems/thread.
// ---------------------------------------------------------------------------
__global__ __launch_bounds__(256) void k_xcast(
    const float* __restrict__ x, unsigned short* __restrict__ xb16)
{
    const size_t i = ((size_t)blockIdx.x * 256 + threadIdx.x) * 8;
    float4 f0 = *(const float4*)(x + i);
    float4 f1 = *(const float4*)(x + i + 4);
    us8 v;
    v[0] = bf16rn(f0.x); v[1] = bf16rn(f0.y); v[2] = bf16rn(f0.z); v[3] = bf16rn(f0.w);
    v[4] = bf16rn(f1.x); v[5] = bf16rn(f1.y); v[6] = bf16rn(f1.z); v[7] = bf16rn(f1.w);
    *(us8*)(xb16 + i) = v;
}

// ---------------------------------------------------------------------------
// Weight pack (unchanged): [k][n] -> MFMA fragment order per BK=64 chunk.
// ---------------------------------------------------------------------------
__global__ __launch_bounds__(256) void k_pack(
    const float* __restrict__ Wq, const float* __restrict__ Wk,
    const float* __restrict__ Wv, const float* __restrict__ Wo,
    const float* __restrict__ W1, const float* __restrict__ W2,
    unsigned short* __restrict__ Wq_pk, unsigned short* __restrict__ Wk_pk,
    unsigned short* __restrict__ Wv_pk, unsigned short* __restrict__ Wo_pk,
    unsigned short* __restrict__ W1_pk, unsigned short* __restrict__ W2_pk)
{
    const int blk = blockIdx.x;
    const float* src; unsigned short* dst; int Ntot = 256, n0 = 0, k0;
    if (blk < 12)      { src = Wq; k0 = blk * 64;        dst = Wq_pk + (size_t)blk * 16384; }
    else if (blk < 24) { src = Wk; k0 = (blk - 12) * 64; dst = Wk_pk + (size_t)(blk - 12) * 16384; }
    else if (blk < 28) { src = Wv; k0 = (blk - 24) * 64; dst = Wv_pk + (size_t)(blk - 24) * 16384; }
    else if (blk < 44) {
        const int i = blk - 28; const int p = i >> 2, c = i & 3;
        src = W1; Ntot = 1024; n0 = p * 256; k0 = c * 64;
        dst = W1_pk + (size_t)i * 16384;
    }
    else if (blk < 60) { src = W2; k0 = (blk - 44) * 64; dst = W2_pk + (size_t)(blk - 44) * 16384; }
    else               { src = Wo; k0 = (blk - 60) * 64; dst = Wo_pk + (size_t)(blk - 60) * 16384; }

    const int tid = threadIdx.x;
    for (int j = 0; j < 8; ++j) {
        const int fi = j * 256 + tid;
        const int lane = fi & 63;
        const int t2 = fi >> 6;          // nt*2+kk
        const int nt = t2 >> 1, kk = t2 & 1;
        const int col = lane & 15, q4 = lane >> 4;
        const int n = n0 + nt * 16 + col;
        const int kbase = k0 + kk * 32 + q4 * 8;
        us8 v;
        #pragma unroll
        for (int e = 0; e < 8; ++e)
            v[e] = bf16rn(src[(size_t)(kbase + e) * Ntot + n]);
        *(us8*)(dst + (size_t)fi * 8) = v;
    }
}

// ---------------------------------------------------------------------------
// Kernel 1: q/k time-conv + v GEMMs. 512 threads / 8 waves. (unchanged)
// ---------------------------------------------------------------------------
__global__ __launch_bounds__(512, 4) void k_qkv_gemm(
    const unsigned short* __restrict__ xb16,
    const unsigned short* __restrict__ Wq_pk, const unsigned short* __restrict__ Wk_pk,
    const unsigned short* __restrict__ Wv_pk,
    const float* __restrict__ bq, const float* __restrict__ bk,
    const float* __restrict__ bv,
    unsigned short* __restrict__ qpk, unsigned short* __restrict__ kpk,
    unsigned short* __restrict__ vpk)
{
    __shared__ __align__(16) unsigned short As[128][72];
    __shared__ __align__(16) unsigned short Bs[16384];   // 32 KB, fragment-linear

    const int tid = threadIdx.x, w = tid >> 6, lane = tid & 63;
    const int col = lane & 15, q4 = lane >> 4;
    const int wr = w >> 2, wc = w & 3;
    const int y = blockIdx.y;
    const int bn = blockIdx.x >> 1, half = blockIdx.x & 1, t0 = half * 128;
    const int nch = (y == 2) ? 4 : 12;
    const unsigned short* Wpk = (y == 0) ? Wq_pk : (y == 1) ? Wk_pk : Wv_pk;

    f32x4 acc[4][4];
    #pragma unroll
    for (int m = 0; m < 4; ++m)
        #pragma unroll
        for (int n = 0; n < 4; ++n)
            acc[m][n] = (f32x4){0.f, 0.f, 0.f, 0.f};

    const int arow = tid >> 2, aq = (tid & 3) * 16;

    for (int c = 0; c < nch; ++c) {
        const int s  = (y == 2) ? 1 : (c >> 2);
        const int c0 = (y == 2) ? (c * 64) : ((c & 3) * 64);

        // A: issue global loads (conv-shifted row; clamp + zero at seq edges)
        const int trow = t0 + s - 1 + arow;
        const bool ok = (trow >= 0) && (trow < 256);
        const int trc = ok ? trow : (trow < 0 ? 0 : 255);
        const unsigned short* ap = xb16 + ((size_t)bn * 256 + trc) * 256 + c0 + aq;
        us8 av[2];
        #pragma unroll
        for (int j = 0; j < 2; ++j)
            av[j] = *(const us8*)(ap + j * 8);

        // B: async global->LDS, 4 x 1KB per wave, fully linear
        const char* wb = (const char*)(Wpk + (size_t)c * 16384);
        #pragma unroll
        for (int r = 0; r < 4; ++r) {
            const int boff = (r * 8 + w) * 1024;
            gload_lds16(wb + boff + lane * 16, ((char*)Bs) + boff);
        }

        // A: write to padded LDS (zero OOB rows)
        #pragma unroll
        for (int j = 0; j < 2; ++j) {
            us8 v = av[j];
            if (!ok) v = (us8){0, 0, 0, 0, 0, 0, 0, 0};
            *(us8*)&As[arow][aq + j * 8] = v;
        }
        __syncthreads();

        #pragma unroll
        for (int kk = 0; kk < 2; ++kk) {
            bfrag a[4], b[4];
            #pragma unroll
            for (int m = 0; m < 4; ++m)
                a[m] = *(const bfrag*)&As[wr * 64 + m * 16 + col][kk * 32 + q4 * 8];
            #pragma unroll
            for (int n = 0; n < 4; ++n)
                b[n] = *(const bfrag*)&Bs[(((wc * 4 + n) * 2 + kk) * 64 + lane) * 8];
            #pragma unroll
            for (int n = 0; n < 4; ++n)
                #pragma unroll
                for (int m = 0; m < 4; ++m)
                    acc[m][n] = __builtin_amdgcn_mfma_f32_16x16x32_bf16(a[m], b[n], acc[m][n], 0, 0, 0);
        }
        __syncthreads();
    }

    if (y == 2) {
        // V: fragment-packed (PV B-operand order), us4 stores (4 consecutive s).
        #pragma unroll
        for (int n = 0; n < 4; ++n) {
            const int nn = wc * 64 + n * 16 + col;
            const int hh = nn >> 5, d = nn & 31;
            const float bb = bv[nn];
            #pragma unroll
            for (int m = 0; m < 4; ++m) {
                const int s0 = t0 + wr * 64 + m * 16 + q4 * 4;
                us4 pk;
                #pragma unroll
                for (int r = 0; r < 4; ++r)
                    pk[r] = bf16rn(acc[m][n][r] + bb);
                const int kc = (s0 >> 5) & 7, q3 = (s0 >> 3) & 3, e0 = s0 & 7;
                *(us4*)(vpk + (((((size_t)bn * 8 + hh) * 8 + kc) * 2 + (d >> 4)) * 64
                               + (d & 15) + 16 * q3) * 8 + e0) = pk;
            }
        }
    } else {
        // Q/K: fragment-packed (QK A/B operand order), scalar u16 stores.
        unsigned short* dst = (y == 0) ? qpk : kpk;
        const float* bias = (y == 0) ? bq : bk;
        #pragma unroll
        for (int n = 0; n < 4; ++n) {
            const int nn = wc * 64 + n * 16 + col;
            const int hh = nn >> 5, hd = nn & 31;
            const float bb = bias[nn];
            #pragma unroll
            for (int m = 0; m < 4; ++m) {
                const int tile = (t0 >> 4) + wr * 4 + m;
                unsigned short* dp = dst
                    + ((((size_t)bn * 8 + hh) * 16 + tile) * 64 + 16 * (hd >> 3)) * 8
                    + (hd & 7);
                #pragma unroll
                for (int r = 0; r < 4; ++r)
                    dp[(q4 * 4 + r) * 8] = bf16rn(acc[m][n][r] + bb);
            }
        }
    }
}

// ---------------------------------------------------------------------------
// Kernel 2: MFMA attention. Two-pass softmax (pass1 max-only, pass2 exp+store)
// cuts live registers from sc[16]=64 to ~4 transient -> VGPR <=128 (4 w/SIMD).
// K AND V fragments read direct from packed global (L2-hot); LDS = Pw only
// (33.8 KB -> 4 blocks/CU). Zero barriers; waves fully independent.
// ---------------------------------------------------------------------------
__global__ __launch_bounds__(256, 4) void k_attn_mfma(
    const unsigned short* __restrict__ qpk, const unsigned short* __restrict__ kpk,
    const unsigned short* __restrict__ vpk, unsigned short* __restrict__ ob)
{
    __shared__ __align__(16) unsigned short Pw[4][16][264];// per-wave P scratch

    const int bn   = blockIdx.x;
    const int h    = blockIdx.y;
    const int tid  = threadIdx.x;
    const int w    = tid >> 6;
    const int lane = tid & 63;
    const int col  = lane & 15;
    const int q4   = lane >> 4;
    const size_t bhi = (size_t)bn * 8 + h;
    const size_t obase = (size_t)bn * S2_ * D_ + h * HD_;
    const unsigned short* qbase = qpk + bhi * 8192;
    const unsigned short* kbase = kpk + bhi * 8192;
    const unsigned short* vbase = vpk + bhi * 8192;
    const float SCL2E = 0.17677669529663687f * 1.4426950408889634f; // 1/sqrt(32)*log2(e)

    for (int mt = 0; mt < 4; ++mt) {
        // ---- Q A-frag (one 16B load, frag-linear) ----
        bfrag qa = *(const bfrag*)(qbase + ((size_t)(w * 4 + mt) * 64 + lane) * 8);

        // ---- pass 1: row max over 256 cols (transient 4-reg MFMA results) ----
        float mx[4] = {-1e30f, -1e30f, -1e30f, -1e30f};
        #pragma unroll
        for (int nt = 0; nt < 16; ++nt) {
            bfrag kf = *(const bfrag*)(kbase + ((size_t)(nt * 64 + lane)) * 8);
            f32x4 z = {0.f, 0.f, 0.f, 0.f};
            f32x4 s = __builtin_amdgcn_mfma_f32_16x16x32_bf16(qa, kf, z, 0, 0, 0);
            #pragma unroll
            for (int r = 0; r < 4; ++r)
                mx[r] = fmaxf(mx[r], s[r]);
        }
        #pragma unroll
        for (int r = 0; r < 4; ++r) {
            mx[r] = fmaxf(mx[r], __shfl_xor(mx[r], 1));
            mx[r] = fmaxf(mx[r], __shfl_xor(mx[r], 2));
            mx[r] = fmaxf(mx[r], __shfl_xor(mx[r], 4));
            mx[r] = fmaxf(mx[r], __shfl_xor(mx[r], 8));
            mx[r] *= SCL2E;   // pre-scaled max for fused exp2 arg
        }

        // ---- pass 2: recompute scores, exp2, accumulate l, store P ----
        float l[4] = {0.f, 0.f, 0.f, 0.f};
        #pragma unroll
        for (int nt = 0; nt < 16; ++nt) {
            bfrag kf = *(const bfrag*)(kbase + ((size_t)(nt * 64 + lane)) * 8);
            f32x4 z = {0.f, 0.f, 0.f, 0.f};
            f32x4 s = __builtin_amdgcn_mfma_f32_16x16x32_bf16(qa, kf, z, 0, 0, 0);
            #pragma unroll
            for (int r = 0; r < 4; ++r) {
                const float e = exp2f(fmaf(s[r], SCL2E, -mx[r]));
                l[r] += e;
                Pw[w][q4 * 4 + r][nt * 16 + col] = bf16rn(e);
            }
        }
        #pragma unroll
        for (int r = 0; r < 4; ++r) {
            l[r] += __shfl_xor(l[r], 1);
            l[r] += __shfl_xor(l[r], 2);
            l[r] += __shfl_xor(l[r], 4);
            l[r] += __shfl_xor(l[r], 8);
        }
        // same-wave DS ordering: reads below see the writes (in-order DS pipe)

        // ---- PV: o[16 x 32], V B-frags direct from packed global ----
        f32x4 oacc[2];
        oacc[0] = (f32x4){0.f, 0.f, 0.f, 0.f};
        oacc[1] = (f32x4){0.f, 0.f, 0.f, 0.f};
        #pragma unroll
        for (int kc = 0; kc < 8; ++kc) {
            bfrag pa = *(const bfrag*)&Pw[w][col][kc * 32 + q4 * 8];
            bfrag v0 = *(const bfrag*)(vbase + ((size_t)(kc * 2 + 0) * 64 + lane) * 8);
            bfrag v1 = *(const bfrag*)(vbase + ((size_t)(kc * 2 + 1) * 64 + lane) * 8);
            oacc[0] = __builtin_amdgcn_mfma_f32_16x16x32_bf16(pa, v0, oacc[0], 0, 0, 0);
            oacc[1] = __builtin_amdgcn_mfma_f32_16x16x32_bf16(pa, v1, oacc[1], 0, 0, 0);
        }

        // ---- normalize + write ----
        const int r0w = w * 64;
        float inv[4];
        #pragma unroll
        for (int r = 0; r < 4; ++r) inv[r] = 1.f / l[r];
        #pragma unroll
        for (int dt = 0; dt < 2; ++dt)
            #pragma unroll
            for (int r = 0; r < 4; ++r)
                ob[obase + (size_t)(r0w + mt * 16 + q4 * 4 + r) * D_ + dt * 16 + col]
                    = bf16rn(oacc[dt][r] * inv[r]);
    }
}

// ---------------------------------------------------------------------------
// Kernel 3: o @ Wo + bo + residual(x) -> LN1 -> hb (bf16), MFMA. (unchanged)
// ---------------------------------------------------------------------------
__global__ __launch_bounds__(256) void k_oproj_gemm(
    const unsigned short* __restrict__ ob,
    const unsigned short* __restrict__ Wo_pk, const float* __restrict__ bo,
    const float* __restrict__ x,
    const float* __restrict__ g1, const float* __restrict__ be1,
    unsigned short* __restrict__ hb)
{
    __shared__ __align__(16) unsigned short As[128][72];
    __shared__ __align__(16) unsigned short Bs[16384];
    __shared__ float red[128][2][2];

    const int tid = threadIdx.x, w = tid >> 6, lane = tid & 63;
    const int col = lane & 15, q4 = lane >> 4;
    const int wr = w >> 1, wc = w & 1;
    const size_t tok0 = (size_t)blockIdx.x * 128;

    f32x4 acc[4][8];
    #pragma unroll
    for (int m = 0; m < 4; ++m)
        #pragma unroll
        for (int n = 0; n < 8; ++n)
            acc[m][n] = (f32x4){0.f, 0.f, 0.f, 0.f};

    const int arow = tid >> 1, ahalf = (tid & 1) * 32;

    for (int c = 0; c < 4; ++c) {
        const unsigned short* ap = ob + (tok0 + arow) * D_ + c * 64 + ahalf;
        us8 av[4];
        #pragma unroll
        for (int j = 0; j < 4; ++j)
            av[j] = *(const us8*)(ap + j * 8);

        const char* wb = (const char*)(Wo_pk + (size_t)c * 16384);
        #pragma unroll
        for (int r = 0; r < 8; ++r) {
            const int boff = (r * 4 + w) * 1024;
            gload_lds16(wb + boff + lane * 16, ((char*)Bs) + boff);
        }

        #pragma unroll
        for (int j = 0; j < 4; ++j)
            *(us8*)&As[arow][ahalf + j * 8] = av[j];
        __syncthreads();

        #pragma unroll
        for (int kk = 0; kk < 2; ++kk) {
            bfrag a[4], b[8];
            #pragma unroll
            for (int m = 0; m < 4; ++m)
                a[m] = *(const bfrag*)&As[wr * 64 + m * 16 + col][kk * 32 + q4 * 8];
            #pragma unroll
            for (int n = 0; n < 8; ++n)
                b[n] = *(const bfrag*)&Bs[(((wc * 8 + n) * 2 + kk) * 64 + lane) * 8];
            #pragma unroll
            for (int n = 0; n < 8; ++n)
                #pragma unroll
                for (int m = 0; m < 4; ++m)
                    acc[m][n] = __builtin_amdgcn_mfma_f32_16x16x32_bf16(a[m], b[n], acc[m][n], 0, 0, 0);
        }
        __syncthreads();
    }

    float bov[8];
    #pragma unroll
    for (int n = 0; n < 8; ++n)
        bov[n] = bo[wc * 128 + n * 16 + col];

    float s[4][4], s2[4][4];
    #pragma unroll
    for (int m = 0; m < 4; ++m)
        #pragma unroll
        for (int r = 0; r < 4; ++r) { s[m][r] = 0.f; s2[m][r] = 0.f; }

    #pragma unroll
    for (int m = 0; m < 4; ++m)
        #pragma unroll
        for (int r = 0; r < 4; ++r) {
            const size_t row = tok0 + wr * 64 + m * 16 + q4 * 4 + r;
            #pragma unroll
            for (int n = 0; n < 8; ++n) {
                const int nn = wc * 128 + n * 16 + col;
                const float yv = acc[m][n][r] + bov[n] + x[row * D_ + nn];
                acc[m][n][r] = yv;
                s[m][r] += yv;
                s2[m][r] = fmaf(yv, yv, s2[m][r]);
            }
        }

    #pragma unroll
    for (int m = 0; m < 4; ++m)
        #pragma unroll
        for (int r = 0; r < 4; ++r) {
            #pragma unroll
            for (int d = 1; d < 16; d <<= 1) {
                s[m][r]  += __shfl_xor(s[m][r],  d);
                s2[m][r] += __shfl_xor(s2[m][r], d);
            }
        }

    if (col == 0) {
        #pragma unroll
        for (int m = 0; m < 4; ++m)
            #pragma unroll
            for (int r = 0; r < 4; ++r) {
                const int rl = wr * 64 + m * 16 + q4 * 4 + r;
                red[rl][wc][0] = s[m][r];
                red[rl][wc][1] = s2[m][r];
            }
    }
    __syncthreads();

    float mu[4][4], rs[4][4];
    #pragma unroll
    for (int m = 0; m < 4; ++m)
        #pragma unroll
        for (int r = 0; r < 4; ++r) {
            const int rl = wr * 64 + m * 16 + q4 * 4 + r;
            const float ts  = red[rl][0][0] + red[rl][1][0];
            const float ts2 = red[rl][0][1] + red[rl][1][1];
            const float m_  = ts * (1.f / 256.f);
            mu[m][r] = m_;
            rs[m][r] = rsqrtf(ts2 * (1.f / 256.f) - m_ * m_ + EPS_);
        }

    #pragma unroll
    for (int n = 0; n < 8; ++n) {
        const int nn = wc * 128 + n * 16 + col;
        const float gv = g1[nn], bev = be1[nn];
        #pragma unroll
        for (int m = 0; m < 4; ++m)
            #pragma unroll
            for (int r = 0; r < 4; ++r) {
                const size_t row = tok0 + wr * 64 + m * 16 + q4 * 4 + r;
                hb[row * D_ + nn] = bf16rn((acc[m][n][r] - mu[m][r]) * rs[m][r] * gv + bev);
            }
    }
}

// ---------------------------------------------------------------------------
// Kernel 4a: ff = leaky(hb @ W1 + b1). (unchanged)
// ---------------------------------------------------------------------------
__global__ __launch_bounds__(256) void k_ffn1_gemm(
    const unsigned short* __restrict__ hb,
    const unsigned short* __restrict__ W1_pk, const float* __restrict__ b1,
    unsigned short* __restrict__ ff)
{
    __shared__ __align__(16) unsigned short As[128][72];
    __shared__ __align__(16) unsigned short Bs[16384];

    const int tid = threadIdx.x, w = tid >> 6, lane = tid & 63;
    const int col = lane & 15, q4 = lane >> 4;
    const int wr = w >> 1, wc = w & 1;
    const size_t tok0 = (size_t)blockIdx.x * 128;
    const int y = blockIdx.y;                 // n-panel
    const unsigned short* Wpk = W1_pk + (size_t)y * 4 * 16384;

    f32x4 acc[4][8];
    #pragma unroll
    for (int m = 0; m < 4; ++m)
        #pragma unroll
        for (int n = 0; n < 8; ++n)
            acc[m][n] = (f32x4){0.f, 0.f, 0.f, 0.f};

    const int arow = tid >> 1, ahalf = (tid & 1) * 32;

    for (int c = 0; c < 4; ++c) {
        const unsigned short* ap = hb + (tok0 + arow) * D_ + c * 64 + ahalf;
        us8 av[4];
        #pragma unroll
        for (int j = 0; j < 4; ++j)
            av[j] = *(const us8*)(ap + j * 8);

        const char* wb = (const char*)(Wpk + (size_t)c * 16384);
        #pragma unroll
        for (int r = 0; r < 8; ++r) {
            const int boff = (r * 4 + w) * 1024;
            gload_lds16(wb + boff + lane * 16, ((char*)Bs) + boff);
        }

        #pragma unroll
        for (int j = 0; j < 4; ++j)
            *(us8*)&As[arow][ahalf + j * 8] = av[j];
        __syncthreads();

        #pragma unroll
        for (int kk = 0; kk < 2; ++kk) {
            bfrag a[4], b[8];
            #pragma unroll
            for (int m = 0; m < 4; ++m)
                a[m] = *(const bfrag*)&As[wr * 64 + m * 16 + col][kk * 32 + q4 * 8];
            #pragma unroll
            for (int n = 0; n < 8; ++n)
                b[n] = *(const bfrag*)&Bs[(((wc * 8 + n) * 2 + kk) * 64 + lane) * 8];
            #pragma unroll
            for (int n = 0; n < 8; ++n)
                #pragma unroll
                for (int m = 0; m < 4; ++m)
                    acc[m][n] = __builtin_amdgcn_mfma_f32_16x16x32_bf16(a[m], b[n], acc[m][n], 0, 0, 0);
        }
        __syncthreads();
    }

    #pragma unroll
    for (int n = 0; n < 8; ++n) {
        const int nglob = y * 256 + wc * 128 + n * 16 + col;
        const float bb = b1[nglob];
        #pragma unroll
        for (int m = 0; m < 4; ++m)
            #pragma unroll
            for (int r = 0; r < 4; ++r) {
                float v = acc[m][n][r] + bb;
                v = (v > 0.f) ? v : NEG_ * v;
                ff[(tok0 + wr * 64 + m * 16 + q4 * 4 + r) * (size_t)F_ + nglob] = bf16rn(v);
            }
    }
}

// ---------------------------------------------------------------------------
// Kernel 4b: out = LN2(ff @ W2 + b2 + hb). (unchanged)
// ---------------------------------------------------------------------------
__global__ __launch_bounds__(256) void k_ffn2_gemm(
    const unsigned short* __restrict__ ff,
    const unsigned short* __restrict__ W2_pk, const float* __restrict__ b2,
    const unsigned short* __restrict__ hb,
    const float* __restrict__ g2, const float* __restrict__ be2,
    float* __restrict__ out)
{
    __shared__ __align__(16) unsigned short As[128][72];
    __shared__ __align__(16) unsigned short Bs[16384];
    __shared__ float red[128][2][2];

    const int tid = threadIdx.x, w = tid >> 6, lane = tid & 63;
    const int col = lane & 15, q4 = lane >> 4;
    const int wr = w >> 1, wc = w & 1;
    const size_t tok0 = (size_t)blockIdx.x * 128;

    f32x4 acc[4][8];
    #pragma unroll
    for (int m = 0; m < 4; ++m)
        #pragma unroll
        for (int n = 0; n < 8; ++n)
            acc[m][n] = (f32x4){0.f, 0.f, 0.f, 0.f};

    const int arow = tid >> 1, ahalf = (tid & 1) * 32;

    for (int c = 0; c < 16; ++c) {
        const unsigned short* ap = ff + (tok0 + arow) * (size_t)F_ + c * 64 + ahalf;
        us8 av[4];
        #pragma unroll
        for (int j = 0; j < 4; ++j)
            av[j] = *(const us8*)(ap + j * 8);

        const char* wb = (const char*)(W2_pk + (size_t)c * 16384);
        #pragma unroll
        for (int r = 0; r < 8; ++r) {
            const int boff = (r * 4 + w) * 1024;
            gload_lds16(wb + boff + lane * 16, ((char*)Bs) + boff);
        }

        #pragma unroll
        for (int j = 0; j < 4; ++j)
            *(us8*)&As[arow][ahalf + j * 8] = av[j];
        __syncthreads();

        #pragma unroll
        for (int kk = 0; kk < 2; ++kk) {
            bfrag a[4], b[8];
            #pragma unroll
            for (int m = 0; m < 4; ++m)
                a[m] = *(const bfrag*)&As[wr * 64 + m * 16 + col][kk * 32 + q4 * 8];
            #pragma unroll
            for (int n = 0; n < 8; ++n)
                b[n] = *(const bfrag*)&Bs[(((wc * 8 + n) * 2 + kk) * 64 + lane) * 8];
            #pragma unroll
            for (int n = 0; n < 8; ++n)
                #pragma unroll
                for (int m = 0; m < 4; ++m)
                    acc[m][n] = __builtin_amdgcn_mfma_f32_16x16x32_bf16(a[m], b[n], acc[m][n], 0, 0, 0);
        }
        __syncthreads();
    }

    float b2v[8];
    #pragma unroll
    for (int n = 0; n < 8; ++n)
        b2v[n] = b2[wc * 128 + n * 16 + col];

    float s[4][4], s2[4][4];
    #pragma unroll
    for (int m = 0; m < 4; ++m)
        #pragma unroll
        for (int r = 0; r < 4; ++r) { s[m][r] = 0.f; s2[m][r] = 0.f; }

    #pragma unroll
    for (int m = 0; m < 4; ++m)
        #pragma unroll
        for (int r = 0; r < 4; ++r) {
            const size_t row = tok0 + wr * 64 + m * 16 + q4 * 4 + r;
            #pragma unroll
            for (int n = 0; n < 8; ++n) {
                const int nn = wc * 128 + n * 16 + col;
                const float yv = acc[m][n][r] + b2v[n] + bf2f(hb[row * D_ + nn]);
                acc[m][n][r] = yv;
                s[m][r] += yv;
                s2[m][r] = fmaf(yv, yv, s2[m][r]);
            }
        }

    #pragma unroll
    for (int m = 0; m < 4; ++m)
        #pragma unroll
        for (int r = 0; r < 4; ++r) {
            #pragma unroll
            for (int d = 1; d < 16; d <<= 1) {
                s[m][r]  += __shfl_xor(s[m][r],  d);
                s2[m][r] += __shfl_xor(s2[m][r], d);
            }
        }

    if (col == 0) {
        #pragma unroll
        for (int m = 0; m < 4; ++m)
            #pragma unroll
            for (int r = 0; r < 4; ++r) {
                const int rl = wr * 64 + m * 16 + q4 * 4 + r;
                red[rl][wc][0] = s[m][r];
                red[rl][wc][1] = s2[m][r];
            }
    }
    __syncthreads();

    float mu[4][4], rs[4][4];
    #pragma unroll
    for (int m = 0; m < 4; ++m)
        #pragma unroll
        for (int r = 0; r < 4; ++r) {
            const int rl = wr * 64 + m * 16 + q4 * 4 + r;
            const float ts  = red[rl][0][0] + red[rl][1][0];
            const float ts2 = red[rl][0][1] + red[rl][1][1];
            const float m_  = ts * (1.f / 256.f);
            mu[m][r] = m_;
            rs[m][r] = rsqrtf(ts2 * (1.f / 256.f) - m_ * m_ + EPS_);
        }

    #pragma unroll
    for (int n = 0; n < 8; ++n) {
        const int nn = wc * 128 + n * 16 + col;
        const float gv = g2[nn], bev = be2[nn];
        #pragma unroll
        for (int m = 0; m < 4; ++m)
            #pragma unroll
            for (int r = 0; r < 4; ++r) {
                const size_t row = tok0 + wr * 64 + m * 16 + q4 * 4 + r;
                out[row * D_ + nn] = (acc[m][n][r] - mu[m][r]) * rs[m][r] * gv + bev;
            }
    }
}

// ---------------------------------------------------------------------------
extern "C" void kernel_launch(void* const* d_in, const int* in_sizes, int n_in,
                              void* d_out, int out_size, void* d_ws, size_t ws_size,
                              hipStream_t stream)
{
    const float* x   = (const float*)d_in[0];
    const float* Wq  = (const float*)d_in[1];
    const float* bq  = (const float*)d_in[2];
    const float* Wk  = (const float*)d_in[3];
    const float* bk  = (const float*)d_in[4];
    const float* Wv  = (const float*)d_in[5];
    const float* bv  = (const float*)d_in[6];
    const float* Wo  = (const float*)d_in[7];
    const float* bo  = (const float*)d_in[8];
    const float* W1  = (const float*)d_in[9];
    const float* b1  = (const float*)d_in[10];
    const float* W2  = (const float*)d_in[11];
    const float* b2  = (const float*)d_in[12];
    const float* g1  = (const float*)d_in[13];
    const float* be1 = (const float*)d_in[14];
    const float* g2  = (const float*)d_in[15];
    const float* be2 = (const float*)d_in[16];
    float* out = (float*)d_out;

    const size_t N = (size_t)B_ * S1_ * S2_ * D_;   // 16,777,216 elements

    unsigned short* qpk = (unsigned short*)d_ws;    // frag-packed per (bn,h)
    unsigned short* kpk = qpk + N;
    unsigned short* vpk = kpk + N;
    unsigned short* ob  = vpk + N;
    float*          h   = (float*)(ob + N);         // region reserved (2N shorts)
    unsigned short* Wq_pk = (unsigned short*)(h + N);
    unsigned short* Wk_pk = Wq_pk + (size_t)12 * 16384;   // 196608
    unsigned short* Wv_pk = Wk_pk + (size_t)12 * 16384;
    unsigned short* Wo_pk = Wv_pk + (size_t)4 * 16384;    // 65536
    unsigned short* W1_pk = Wo_pk + (size_t)4 * 16384;
    unsigned short* W2_pk = W1_pk + (size_t)16 * 16384;   // 262144
    const size_t need = (size_t)(W2_pk + (size_t)16 * 16384 - (unsigned short*)d_ws) * 2;
    if (ws_size < need) return;

    // Aliases (lifetime-disjoint):
    unsigned short* xb16 = (unsigned short*)h;   // dead after k_qkv_gemm
    unsigned short* hb   = (unsigned short*)h;   // written by oproj (after xb16 dead)
    unsigned short* ff   = qpk;                  // spans qpk..ob; all dead after oproj

    k_xcast     <<<dim3((unsigned)(N / 2048)), 256, 0, stream>>>(x, xb16);
    k_pack      <<<dim3(64), 256, 0, stream>>>(Wq, Wk, Wv, Wo, W1, W2,
                    Wq_pk, Wk_pk, Wv_pk, Wo_pk, W1_pk, W2_pk);
    k_qkv_gemm  <<<dim3(512, 3), 512, 0, stream>>>(
                    xb16, Wq_pk, Wk_pk, Wv_pk, bq, bk, bv, qpk, kpk, vpk);
    k_attn_mfma <<<dim3(B_ * S1_, H_), 256, 0, stream>>>(qpk, kpk, vpk, ob);
    k_oproj_gemm<<<dim3(512), 256, 0, stream>>>(
                    ob, Wo_pk, bo, x, g1, be1, hb);
    k_ffn1_gemm <<<dim3(512, 4), 256, 0, stream>>>(hb, W1_pk, b1, ff);
    k_ffn2_gemm <<<dim3(512), 256, 0, stream>>>(ff, W2_pk, b2, hb, g2, be2, out);
}